// Round 6
// baseline (334.474 us; speedup 1.0000x reference)
//
#include <hip/hip_runtime.h>

// NetVLAD — split design, spill-free (round 6). B=32, N=4096, D=256, K=128, Dc=64.
// kA (256 blocks x 1024 thr, __launch_bounds__(1024,4) -> 128 VGPR, 4 w/SIMD):
//   per 16-row wave-tile: X->A-frags, GEMM1 (8 Wa kt, all acc live), exp,
//   in-wave rowsum, store NORMALIZED assign P[b,k,n] bf16; GEMM2 (h), leaky,
//   wave-private LDS transpose; GEMM3 (sq raw) -> LDS transpose -> S[b,d,n].
// kB (B*P2 blocks x 512 thr, no LDS, 4 w/SIMD): agg[b,k,d] = sum_n P*S via
//   MFMA, frags loaded directly from global (n-contiguous 16B/lane);
//   mass via constant ones B-frag. Per-(b,nc) fp32 partials.
// kC (32 blocks): reduce P2 partials, vlad = agg - mass*centroid, normalize.
// MFMA 16x16x32 layouts (m89/m120-verified):
//   A: lane holds A[m=lane&15][k=(lane>>4)*8+j]
//   B: lane holds B[k=(lane>>4)*8+j][n=lane&15]
//   C/D: lane holds D[row=(lane>>4)*4+reg][col=lane&15]

#define B_   32
#define N_   4096
#define D_   256
#define K_   128
#define DC_  64
#define NEG  0.01f
#define TPB_A 1024

typedef __attribute__((ext_vector_type(8))) short bf16x8;
typedef __attribute__((ext_vector_type(4))) float f32x4;

// kA LDS map (dynamic, 143360 B -> 1 block/CU)
#define WA_OFF   0        // 8kt x 8ks x 64 x 16 = 65536
#define W1_OFF   65536    // 4et x 8ks x 64 x 16 = 32768
#define W2_OFF   98304    // 4ft x 2ks x 64 x 16 = 8192
#define HB_OFF   106496   // 16 waves x 2304 B
#define LDSA_BYTES 143360

__device__ __forceinline__ unsigned ppack(float a, float b) {
  union { float f; unsigned u; } A, Bv; A.f = a; Bv.f = b;
  return __builtin_amdgcn_perm(Bv.u + 0x8000u, A.u + 0x8000u, 0x07060302u);
}
__device__ __forceinline__ unsigned short f2bf(float x) {
  union { float f; unsigned u; } v; v.f = x;
  return (unsigned short)((v.u + 0x8000u) >> 16);
}

__global__ __launch_bounds__(TPB_A, 4)
void netvlad_kA(const float* __restrict__ desc, const float* __restrict__ W1,
                const float* __restrict__ b1, const float* __restrict__ W2,
                const float* __restrict__ b2, const float* __restrict__ Wa,
                const float* __restrict__ ba,
                unsigned short* __restrict__ Pt, unsigned short* __restrict__ St)
{
  extern __shared__ char smem[];
  const int t    = threadIdx.x;
  const int b    = blockIdx.x >> 3;
  const int nc   = blockIdx.x & 7;
  const int w    = t >> 6;
  const int lane = t & 63;
  const int li   = lane & 15;
  const int quad = lane >> 4;

  // ---- one-time: weights -> frag-order bf16 LDS ----
  for (int p = t; p < 6656; p += TPB_A) {
    const float* src;
    if (p < 4096) {            // WaF
      int kt = p >> 9, ks = (p >> 6) & 7, L = p & 63;
      src = Wa + (size_t)(kt * 16 + (L & 15)) * D_ + ks * 32 + ((L >> 4) << 3);
    } else if (p < 6144) {     // W1F
      int q = p - 4096; int et = q >> 9, ks = (q >> 6) & 7, L = q & 63;
      src = W1 + (size_t)(et * 16 + (L & 15)) * D_ + ks * 32 + ((L >> 4) << 3);
    } else {                   // W2F
      int q = p - 6144; int ft = q >> 7, ks = (q >> 6) & 1, L = q & 63;
      src = W2 + (size_t)(ft * 16 + (L & 15)) * DC_ + ks * 32 + ((L >> 4) << 3);
    }
    float4 a = ((const float4*)src)[0], c = ((const float4*)src)[1];
    uint4 o;
    o.x = ppack(a.x, a.y); o.y = ppack(a.z, a.w);
    o.z = ppack(c.x, c.y); o.w = ppack(c.z, c.w);
    *reinterpret_cast<uint4*>(smem + (size_t)p * 16) = o;
  }

  float bar[8], b1r[4], b2r[4];
  #pragma unroll
  for (int kt = 0; kt < 8; ++kt) bar[kt] = ba[kt * 16 + li];
  #pragma unroll
  for (int et = 0; et < 4; ++et) b1r[et] = b1[et * 16 + li];
  #pragma unroll
  for (int ft = 0; ft < 4; ++ft) b2r[ft] = b2[ft * 16 + li];

  __syncthreads();   // weights ready — only barrier

  const int hb = HB_OFF + w * 2304;   // wave-private scratch

  for (int T = 0; T < 2; ++T) {
    const int n_g = nc * 512 + w * 32 + T * 16;
    const float* xrow = desc + ((size_t)b * N_ + n_g + li) * D_ + quad * 8;

    // ---- X: global -> A-frags ----
    bf16x8 xa[8];
    #pragma unroll
    for (int hh = 0; hh < 2; ++hh) {
      float4 xf[4][2];
      #pragma unroll
      for (int k2 = 0; k2 < 4; ++k2) {
        const float* s = xrow + (hh * 4 + k2) * 32;
        xf[k2][0] = ((const float4*)s)[0];
        xf[k2][1] = ((const float4*)s)[1];
      }
      #pragma unroll
      for (int k2 = 0; k2 < 4; ++k2) {
        union { uint4 u; bf16x8 v; } z;
        z.u.x = ppack(xf[k2][0].x, xf[k2][0].y);
        z.u.y = ppack(xf[k2][0].z, xf[k2][0].w);
        z.u.z = ppack(xf[k2][1].x, xf[k2][1].y);
        z.u.w = ppack(xf[k2][1].z, xf[k2][1].w);
        xa[hh * 4 + k2] = z.v;
      }
    }

    // ---- GEMM1: logits for all 8 Wa kt (acc live for post-sum normalize) ----
    f32x4 acc8[8];
    #pragma unroll
    for (int kt = 0; kt < 8; ++kt)
      acc8[kt] = (f32x4){bar[kt], bar[kt], bar[kt], bar[kt]};
    #pragma unroll
    for (int ks = 0; ks < 8; ++ks) {
      #pragma unroll
      for (int kt = 0; kt < 8; ++kt) {
        bf16x8 wb = *reinterpret_cast<const bf16x8*>(
            smem + WA_OFF + ((kt * 8 + ks) * 64 + lane) * 16);
        acc8[kt] = __builtin_amdgcn_mfma_f32_16x16x32_bf16(xa[ks], wb, acc8[kt], 0, 0, 0);
      }
    }
    // exp + row sums (no max pass: |logit| < ~6)
    float sr0 = 0.f, sr1 = 0.f, sr2 = 0.f, sr3 = 0.f;
    #pragma unroll
    for (int kt = 0; kt < 8; ++kt) {
      acc8[kt][0] = __expf(acc8[kt][0]); sr0 += acc8[kt][0];
      acc8[kt][1] = __expf(acc8[kt][1]); sr1 += acc8[kt][1];
      acc8[kt][2] = __expf(acc8[kt][2]); sr2 += acc8[kt][2];
      acc8[kt][3] = __expf(acc8[kt][3]); sr3 += acc8[kt][3];
    }
    #pragma unroll
    for (int off = 1; off < 16; off <<= 1) {
      sr0 += __shfl_xor(sr0, off, 64); sr1 += __shfl_xor(sr1, off, 64);
      sr2 += __shfl_xor(sr2, off, 64); sr3 += __shfl_xor(sr3, off, 64);
    }
    const float inv0 = 1.f / sr0, inv1 = 1.f / sr1;
    const float inv2 = 1.f / sr2, inv3 = 1.f / sr3;
    // store normalized assign: P[b][k][n], k = kt*16+li, n = n_g + quad*4 + r
    #pragma unroll
    for (int kt = 0; kt < 8; ++kt) {
      uint2 pk;
      pk.x = ppack(acc8[kt][0] * inv0, acc8[kt][1] * inv1);
      pk.y = ppack(acc8[kt][2] * inv2, acc8[kt][3] * inv3);
      *reinterpret_cast<uint2*>(
          Pt + ((size_t)b * K_ + kt * 16 + li) * N_ + n_g + quad * 4) = pk;
    }

    // ---- GEMM2: h = leaky(X@W1^T+b1) -> wave-private LDS transpose ----
    {
      f32x4 accH[4];
      #pragma unroll
      for (int et = 0; et < 4; ++et)
        accH[et] = (f32x4){b1r[et], b1r[et], b1r[et], b1r[et]};
      #pragma unroll
      for (int ks = 0; ks < 8; ++ks) {
        #pragma unroll
        for (int et = 0; et < 4; ++et) {
          bf16x8 wb = *reinterpret_cast<const bf16x8*>(
              smem + W1_OFF + ((et * 8 + ks) * 64 + lane) * 16);
          accH[et] = __builtin_amdgcn_mfma_f32_16x16x32_bf16(xa[ks], wb, accH[et], 0, 0, 0);
        }
      }
      #pragma unroll
      for (int et = 0; et < 4; ++et) {
        #pragma unroll
        for (int r = 0; r < 4; ++r) {
          float h = accH[et][r];
          h = h >= 0.f ? h : NEG * h;
          *reinterpret_cast<unsigned short*>(
              smem + hb + (quad * 4 + r) * 144 + (et * 16 + li) * 2) = f2bf(h);
        }
      }
    }
    // same-wave ds ordering: reads below see writes above
    bf16x8 hA0 = *reinterpret_cast<const bf16x8*>(smem + hb + li * 144 + quad * 16);
    bf16x8 hA1 = *reinterpret_cast<const bf16x8*>(smem + hb + li * 144 + 64 + quad * 16);

    // ---- GEMM3: sq = h@W2^T+b2 (raw); transpose -> S[b][d][n] ----
    #pragma unroll
    for (int ft = 0; ft < 4; ++ft) {
      f32x4 sacc = (f32x4){b2r[ft], b2r[ft], b2r[ft], b2r[ft]};
      bf16x8 wf0 = *reinterpret_cast<const bf16x8*>(
          smem + W2_OFF + ((ft * 2 + 0) * 64 + lane) * 16);
      sacc = __builtin_amdgcn_mfma_f32_16x16x32_bf16(hA0, wf0, sacc, 0, 0, 0);
      bf16x8 wf1 = *reinterpret_cast<const bf16x8*>(
          smem + W2_OFF + ((ft * 2 + 1) * 64 + lane) * 16);
      sacc = __builtin_amdgcn_mfma_f32_16x16x32_bf16(hA1, wf1, sacc, 0, 0, 0);
      uint2 pk;
      pk.x = ppack(sacc[0], sacc[1]);
      pk.y = ppack(sacc[2], sacc[3]);
      *reinterpret_cast<uint2*>(smem + hb + (ft * 16 + li) * 32 + quad * 8) = pk;
    }
    #pragma unroll
    for (int i = 0; i < 2; ++i) {
      const int s = lane + i * 64;          // s = d*2 + h8
      const int d = s >> 1, h8 = s & 1;
      bf16x8 sv = *reinterpret_cast<const bf16x8*>(smem + hb + s * 16);
      *reinterpret_cast<bf16x8*>(St + ((size_t)b * DC_ + d) * N_ + n_g + h8 * 8) = sv;
    }
  }
}

__global__ __launch_bounds__(512)
void netvlad_kB(const unsigned short* __restrict__ Pt,
                const unsigned short* __restrict__ St,
                float* __restrict__ aggP, float* __restrict__ massP,
                int ncShift, int ncMask, int nper, int sCount)
{
  const int t    = threadIdx.x;
  const int b    = blockIdx.x >> ncShift;
  const int nc   = blockIdx.x & ncMask;
  const int w    = t >> 6;          // k-tile 0..7
  const int lane = t & 63;
  const int li   = lane & 15;
  const int quad = lane >> 4;

  f32x4 gacc[4], macc;
  #pragma unroll
  for (int nt = 0; nt < 4; ++nt) gacc[nt] = (f32x4){0.f, 0.f, 0.f, 0.f};
  macc = (f32x4){0.f, 0.f, 0.f, 0.f};

  // ones B-frag: column 0 of B == 1.0 -> D[:,0] = row sums (mass)
  const short ob = (li == 0) ? (short)0x3F80 : (short)0;
  const bf16x8 ones = (bf16x8){ob, ob, ob, ob, ob, ob, ob, ob};

  const unsigned short* paBase = Pt + ((size_t)b * K_ + w * 16 + li) * N_;
  const unsigned short* sbBase = St + ((size_t)b * DC_ + li) * N_;
  const int nbase = nc * nper + quad * 8;

  #pragma unroll 4
  for (int s = 0; s < sCount; ++s) {
    const int n0 = nbase + s * 32;
    bf16x8 a = *reinterpret_cast<const bf16x8*>(paBase + n0);
    #pragma unroll
    for (int nt = 0; nt < 4; ++nt) {
      bf16x8 bn = *reinterpret_cast<const bf16x8*>(sbBase + nt * 16 * N_ + n0);
      gacc[nt] = __builtin_amdgcn_mfma_f32_16x16x32_bf16(a, bn, gacc[nt], 0, 0, 0);
    }
    macc = __builtin_amdgcn_mfma_f32_16x16x32_bf16(a, ones, macc, 0, 0, 0);
  }

  float* ab = aggP + ((size_t)(b << ncShift) + nc) * (K_ * DC_);
  #pragma unroll
  for (int nt = 0; nt < 4; ++nt)
    #pragma unroll
    for (int r = 0; r < 4; ++r)
      ab[(w * 16 + quad * 4 + r) * DC_ + nt * 16 + li] = gacc[nt][r];
  if (li == 0) {
    float* mb = massP + ((size_t)(b << ncShift) + nc) * K_;
    #pragma unroll
    for (int r = 0; r < 4; ++r)
      mb[w * 16 + quad * 4 + r] = macc[r];
  }
}

__global__ __launch_bounds__(1024)
void netvlad_kC(const float* __restrict__ aggP, const float* __restrict__ massP,
                const float* __restrict__ centroid, float* __restrict__ out, int P2)
{
  __shared__ float v[K_ * DC_];
  __shared__ float ms[K_];
  __shared__ float red[16];
  const int b = blockIdx.x, t = threadIdx.x;
  if (t < K_) {
    float s = 0.f;
    for (int p = 0; p < P2; ++p) s += massP[(size_t)(b * P2 + p) * K_ + t];
    ms[t] = s;
  }
  __syncthreads();
  float ss = 0.f;
  for (int i = t; i < K_ * DC_; i += 1024) {
    float s = 0.f;
    for (int p = 0; p < P2; ++p) s += aggP[(size_t)(b * P2 + p) * (K_ * DC_) + i];
    float val = s - ms[i >> 6] * centroid[i];
    v[i] = val;
    ss += val * val;
  }
  #pragma unroll
  for (int off = 32; off > 0; off >>= 1) ss += __shfl_down(ss, off, 64);
  if ((t & 63) == 0) red[t >> 6] = ss;
  __syncthreads();
  if (t == 0) {
    float s = 0.f;
    #pragma unroll
    for (int i = 0; i < 16; ++i) s += red[i];
    red[0] = 1.0f / fmaxf(sqrtf(s), 1e-12f);
  }
  __syncthreads();
  const float inv = red[0];
  for (int i = t; i < K_ * DC_; i += 1024)
    out[(size_t)b * (K_ * DC_) + i] = v[i] * inv;
}

extern "C" void kernel_launch(void* const* d_in, const int* in_sizes, int n_in,
                              void* d_out, int out_size, void* d_ws, size_t ws_size,
                              hipStream_t stream) {
  const float* desc     = (const float*)d_in[0];
  const float* W1       = (const float*)d_in[1];
  const float* b1       = (const float*)d_in[2];
  const float* W2       = (const float*)d_in[3];
  const float* b2       = (const float*)d_in[4];
  const float* Wa       = (const float*)d_in[5];
  const float* ba       = (const float*)d_in[6];
  const float* centroid = (const float*)d_in[7];
  float* out = (float*)d_out;

  // ws carve-up: Pt 33.5 MB, St 16.8 MB, then P2 partials (fp32).
  char* p = (char*)d_ws;
  unsigned short* Pt = (unsigned short*)p;  p += (size_t)B_ * K_ * N_ * 2;
  unsigned short* St = (unsigned short*)p;  p += (size_t)B_ * DC_ * N_ * 2;
  const size_t base = (size_t)(p - (char*)d_ws);
  const size_t perP = (size_t)B_ * (K_ * DC_ + K_) * sizeof(float);  // per partial
  int P2 = 16;
  if (ws_size < base + 16 * perP) P2 = 8;
  if (ws_size < base + 8 * perP)  P2 = 4;
  const int ncShift = (P2 == 16) ? 4 : (P2 == 8 ? 3 : 2);
  const int nper = N_ / P2, sCount = nper / 32;

  float* aggP  = (float*)p;  p += (size_t)B_ * P2 * K_ * DC_ * sizeof(float);
  float* massP = (float*)p;

  hipFuncSetAttribute(reinterpret_cast<const void*>(netvlad_kA),
                      hipFuncAttributeMaxDynamicSharedMemorySize, LDSA_BYTES);

  netvlad_kA<<<dim3(B_ * 8), dim3(TPB_A), LDSA_BYTES, stream>>>(
      desc, W1, b1, W2, b2, Wa, ba, Pt, St);
  netvlad_kB<<<dim3(B_ * P2), dim3(512), 0, stream>>>(
      Pt, St, aggP, massP, ncShift, P2 - 1, nper, sCount);
  netvlad_kC<<<dim3(B_), dim3(1024), 0, stream>>>(aggP, massP, centroid, out, P2);
}